// Round 15
// baseline (203.192 us; speedup 1.0000x reference)
//
#include <hip/hip_runtime.h>
#include <hip/hip_bf16.h>

#define FDIM 64
#define BNODES 64          // nodes per bucket (dst >> 6)
#define CHUNK 2048         // edges per partition chunk (391 chunks -> 1.5 blocks/CU)
#define HP 72              // padded LDS row stride in shorts
#define GCAP 2048          // staged edge-index capacity per gather block (32 nodes)

typedef short bf16x8 __attribute__((ext_vector_type(8)));
typedef float f32x4 __attribute__((ext_vector_type(4)));

__device__ __forceinline__ unsigned short f2bf(float f) {
    unsigned int u = __float_as_uint(f);
    unsigned int r = (u + 0x7fffu + ((u >> 16) & 1u)) >> 16;   // RNE
    return (unsigned short)r;
}
__device__ __forceinline__ float bflo(unsigned int p) { return __uint_as_float(p << 16); }
__device__ __forceinline__ float bfhi(unsigned int p) { return __uint_as_float(p & 0xffff0000u); }

// ---- fused: cast features (blocks [0,ncast)) + transpose 6 weight matrices
// (blocks [ncast,ncast+6)) + per-chunk bucket histogram (blocks [ncast+6, ...)) ----
__global__ __launch_bounds__(256) void cast_prep_hist(const float* __restrict__ x,
                                                      unsigned short* __restrict__ xb, int n4,
                                                      int ncast,
                                                      const float* __restrict__ W10,
                                                      const float* __restrict__ W20,
                                                      const float* __restrict__ W11,
                                                      const float* __restrict__ W21,
                                                      const float* __restrict__ W12,
                                                      const float* __restrict__ W22,
                                                      unsigned short* __restrict__ wt,
                                                      const int* __restrict__ dst,
                                                      int* __restrict__ hist,
                                                      int n_edges, int nbuck) {
    int tid = threadIdx.x;
    if (blockIdx.x < (unsigned)ncast) {
        int i = blockIdx.x * 256 + tid;
        if (i < n4) {
            float4 v = ((const float4*)x)[i];
            uint2 o;
            o.x = (unsigned int)f2bf(v.x) | ((unsigned int)f2bf(v.y) << 16);
            o.y = (unsigned int)f2bf(v.z) | ((unsigned int)f2bf(v.w) << 16);
            ((uint2*)xb)[i] = o;
        }
        return;
    }
    if (blockIdx.x < (unsigned)(ncast + 6)) {
        __shared__ unsigned short s[64 * 64];
        int wsel = blockIdx.x - ncast;     // 0..5
        const float* W;
        switch (wsel) {
            case 0: W = W10; break;
            case 1: W = W20; break;
            case 2: W = W11; break;
            case 3: W = W21; break;
            case 4: W = W12; break;
            default: W = W22; break;
        }
#pragma unroll
        for (int p = 0; p < 4; p++) {
            int idx = tid + p * 256;          // 0..1023
            int k = idx >> 4;
            int n0 = (idx & 15) * 4;
            float4 v = ((const float4*)W)[idx];
            s[(n0 + 0) * 64 + k] = f2bf(v.x);
            s[(n0 + 1) * 64 + k] = f2bf(v.y);
            s[(n0 + 2) * 64 + k] = f2bf(v.z);
            s[(n0 + 3) * 64 + k] = f2bf(v.w);
        }
        __syncthreads();
        uint4* o = (uint4*)(wt + (size_t)wsel * 4096);
#pragma unroll
        for (int p = 0; p < 2; p++) {
            int idx = tid + p * 256;          // 0..511
            o[idx] = ((uint4*)s)[idx];
        }
        return;
    }
    // histogram branch
    {
        __shared__ int lh[1024];
        int chunk = blockIdx.x - ncast - 6;
        for (int i = tid; i < nbuck; i += 256) lh[i] = 0;
        __syncthreads();
        int beg = chunk * CHUNK;
        int end = min(beg + CHUNK, n_edges);
        for (int e = beg + tid; e < end; e += 256)
            atomicAdd(&lh[dst[e] >> 6], 1);
        __syncthreads();
        for (int i = tid; i < nbuck; i += 256)
            hist[(size_t)chunk * nbuck + i] = lh[i];
    }
}

// ---- pass 2a: per-bucket exclusive scan over chunks (nchunks <= 512) ----
__global__ __launch_bounds__(512) void scan_chunks(const int* __restrict__ hist,
                                                   int* __restrict__ chunk_off,
                                                   int* __restrict__ bucket_total,
                                                   int nchunks, int nbuck) {
    __shared__ int s[512];
    int b = blockIdx.x;
    int t = threadIdx.x;
    int v = (t < nchunks) ? hist[(size_t)t * nbuck + b] : 0;
    s[t] = v;
    __syncthreads();
    for (int off = 1; off < 512; off <<= 1) {
        int u = (t >= off) ? s[t - off] : 0;
        __syncthreads();
        s[t] += u;
        __syncthreads();
    }
    if (t < nchunks) chunk_off[(size_t)t * nbuck + b] = s[t] - v;  // exclusive
    if (t == 511) bucket_total[b] = s[511];
}

// ---- pass 2b: exclusive scan of bucket totals ----
__global__ __launch_bounds__(1024) void scan_buckets(const int* __restrict__ bucket_total,
                                                     int* __restrict__ bucket_start,
                                                     int* __restrict__ row_ptr,
                                                     int nbuck, int n_nodes, int n_edges) {
    __shared__ int s[1024];
    int t = threadIdx.x;
    int v = (t < nbuck) ? bucket_total[t] : 0;
    s[t] = v;
    __syncthreads();
    for (int off = 1; off < 1024; off <<= 1) {
        int u = (t >= off) ? s[t - off] : 0;
        __syncthreads();
        s[t] += u;
        __syncthreads();
    }
    if (t < nbuck) bucket_start[t] = s[t] - v;
    if (t == 0) { bucket_start[nbuck] = n_edges; row_ptr[n_nodes] = n_edges; }
}

// ---- pass 3: fill packed edges, (chunk,bucket)-contiguous runs ----
__global__ __launch_bounds__(256) void bucket_fill(const int* __restrict__ src,
                                                   const int* __restrict__ dst,
                                                   const int* __restrict__ bucket_start,
                                                   const int* __restrict__ chunk_off,
                                                   unsigned int* __restrict__ packed,
                                                   int n_edges, int nbuck) {
    __shared__ int cur[1024];
    int chunk = blockIdx.x;
    for (int i = threadIdx.x; i < nbuck; i += 256)
        cur[i] = bucket_start[i] + chunk_off[(size_t)chunk * nbuck + i];
    __syncthreads();
    int beg = chunk * CHUNK;
    int end = min(beg + CHUNK, n_edges);
    for (int e = beg + threadIdx.x; e < end; e += 256) {
        int d = dst[e];
        int b = d >> 6;
        int pos = atomicAdd(&cur[b], 1);
        packed[pos] = (unsigned int)src[e] | ((unsigned int)(d & 63) << 16);
    }
}

// ---- pass 4: within-bucket sort to node granularity + row_ptr emit ----
__global__ __launch_bounds__(256) void sort_bucket(const unsigned int* __restrict__ packed,
                                                   const int* __restrict__ bucket_start,
                                                   int* __restrict__ src_sorted,
                                                   int* __restrict__ row_ptr, int n_nodes) {
    __shared__ int cnt[BNODES];
    __shared__ int cur[BNODES];
    int b = blockIdx.x;
    int beg = bucket_start[b], end = bucket_start[b + 1];
    if (threadIdx.x < BNODES) cnt[threadIdx.x] = 0;
    __syncthreads();
    for (int e = beg + threadIdx.x; e < end; e += 256)
        atomicAdd(&cnt[packed[e] >> 16], 1);
    __syncthreads();
    if (threadIdx.x < 64) {
        int v = cnt[threadIdx.x];
        int inc = v;
#pragma unroll
        for (int off = 1; off < 64; off <<= 1) {
            int u = __shfl_up(inc, off, 64);
            if (threadIdx.x >= off) inc += u;
        }
        cur[threadIdx.x] = beg + inc - v;     // exclusive
        int node = b * BNODES + threadIdx.x;
        if (node < n_nodes) row_ptr[node] = beg + inc - v;
    }
    __syncthreads();
    for (int e = beg + threadIdx.x; e < end; e += 256) {
        unsigned int p = packed[e];
        int pos = atomicAdd(&cur[p >> 16], 1);
        src_sorted[pos] = (int)(p & 0xFFFFu);
    }
}

// gather (bf16 in/out, fp32 accum): 32 nodes/block, 8 threads/node, 16B/lane loads.
__global__ __launch_bounds__(256) void gather_bf16(const unsigned short* __restrict__ xb,
                                                   const int* __restrict__ row_ptr,
                                                   const int* __restrict__ src_sorted,
                                                   unsigned short* __restrict__ hb,
                                                   int n_nodes) {
    __shared__ int sidx[GCAP];
    int base = blockIdx.x * 32;
    int ebeg = row_ptr[base];
    int eend = row_ptr[min(base + 32, n_nodes)];
    int total = eend - ebeg;
    int cnt = min(total, GCAP);
    for (int i = threadIdx.x; i < cnt; i += 256) sidx[i] = src_sorted[ebeg + i];
    __syncthreads();

    int t = threadIdx.x;
    int node = base + (t >> 3);
    if (node >= n_nodes) return;
    int c = (t & 7) * 8;                  // 8 bf16 = 16B per lane
    int dbeg = row_ptr[node] - ebeg;
    int dend = row_ptr[node + 1] - ebeg;
    int dmid = (total <= GCAP) ? dend : min(dend, cnt);

    float acc[8];
    {
        uint4 v = *(const uint4*)(xb + (size_t)node * FDIM + c);
        acc[0] = bflo(v.x); acc[1] = bfhi(v.x);
        acc[2] = bflo(v.y); acc[3] = bfhi(v.y);
        acc[4] = bflo(v.z); acc[5] = bfhi(v.z);
        acc[6] = bflo(v.w); acc[7] = bfhi(v.w);
    }

    int e = dbeg;
    for (; e + 7 < dmid; e += 8) {
        int s[8];
#pragma unroll
        for (int j = 0; j < 8; j++) s[j] = sidx[e + j];
        uint4 v[8];
#pragma unroll
        for (int j = 0; j < 8; j++) v[j] = *(const uint4*)(xb + (size_t)s[j] * FDIM + c);
#pragma unroll
        for (int j = 0; j < 8; j++) {
            acc[0] += bflo(v[j].x); acc[1] += bfhi(v[j].x);
            acc[2] += bflo(v[j].y); acc[3] += bfhi(v[j].y);
            acc[4] += bflo(v[j].z); acc[5] += bfhi(v[j].z);
            acc[6] += bflo(v[j].w); acc[7] += bfhi(v[j].w);
        }
    }
    if (e + 3 < dmid) {
        int s[4];
#pragma unroll
        for (int j = 0; j < 4; j++) s[j] = sidx[e + j];
        uint4 v[4];
#pragma unroll
        for (int j = 0; j < 4; j++) v[j] = *(const uint4*)(xb + (size_t)s[j] * FDIM + c);
#pragma unroll
        for (int j = 0; j < 4; j++) {
            acc[0] += bflo(v[j].x); acc[1] += bfhi(v[j].x);
            acc[2] += bflo(v[j].y); acc[3] += bfhi(v[j].y);
            acc[4] += bflo(v[j].z); acc[5] += bfhi(v[j].z);
            acc[6] += bflo(v[j].w); acc[7] += bfhi(v[j].w);
        }
        e += 4;
    }
    for (; e < dmid; e++) {
        uint4 v = *(const uint4*)(xb + (size_t)sidx[e] * FDIM + c);
        acc[0] += bflo(v.x); acc[1] += bfhi(v.x);
        acc[2] += bflo(v.y); acc[3] += bfhi(v.y);
        acc[4] += bflo(v.z); acc[5] += bfhi(v.z);
        acc[6] += bflo(v.w); acc[7] += bfhi(v.w);
    }
    for (; e < dend; e++) {               // overflow tail (virtually never)
        uint4 v = *(const uint4*)(xb + (size_t)src_sorted[ebeg + e] * FDIM + c);
        acc[0] += bflo(v.x); acc[1] += bfhi(v.x);
        acc[2] += bflo(v.y); acc[3] += bfhi(v.y);
        acc[4] += bflo(v.z); acc[5] += bfhi(v.z);
        acc[6] += bflo(v.w); acc[7] += bfhi(v.w);
    }

    uint4 p;
    p.x = (unsigned int)f2bf(acc[0]) | ((unsigned int)f2bf(acc[1]) << 16);
    p.y = (unsigned int)f2bf(acc[2]) | ((unsigned int)f2bf(acc[3]) << 16);
    p.z = (unsigned int)f2bf(acc[4]) | ((unsigned int)f2bf(acc[5]) << 16);
    p.w = (unsigned int)f2bf(acc[6]) | ((unsigned int)f2bf(acc[7]) << 16);
    *(uint4*)(hb + (size_t)node * FDIM + c) = p;
}

// ---- MFMA MLP over a 64-node tile; weights pre-transposed bf16 [n][k] in global ----
__global__ __launch_bounds__(256) void mlp_mfma(const unsigned short* __restrict__ xb,
        const unsigned short* __restrict__ wt1, const float* __restrict__ b1,
        const unsigned short* __restrict__ wt2, const float* __restrict__ b2,
        const float* __restrict__ Wl, const float* __restrict__ bl,
        unsigned short* __restrict__ y, float* __restrict__ out,
        int n_nodes, int do_final) {
    __shared__ unsigned short sH[64 * HP];      // H -> G -> O (bf16)
    __shared__ unsigned short sW1t[64 * HP];    // W1^T [n][k] bf16
    __shared__ unsigned short sW2t[64 * HP];    // W2^T [n][k] bf16
    __shared__ float sb1[FDIM], sb2[FDIM];
    __shared__ float sWl[FDIM * 10];
    __shared__ float sbl[16];

    int tid = threadIdx.x;
    int base = blockIdx.x * 64;

    {
        const uint4* w1g = (const uint4*)wt1;
        const uint4* w2g = (const uint4*)wt2;
#pragma unroll
        for (int p = 0; p < 2; p++) {
            int idx = tid + p * 256;       // 0..511
            int r = idx >> 3, q = idx & 7;
            *(uint4*)(&sW1t[r * HP + q * 8]) = w1g[idx];
            *(uint4*)(&sW2t[r * HP + q * 8]) = w2g[idx];
        }
    }
    if (tid < FDIM) { sb1[tid] = b1[tid]; sb2[tid] = b2[tid]; }
    if (do_final) {
        for (int i = tid; i < FDIM * 10; i += 256) sWl[i] = Wl[i];
        if (tid < 10) sbl[tid] = bl[tid];
    }
#pragma unroll
    for (int p = 0; p < 2; p++) {
        int idx = tid + p * 256;
        int r = idx >> 3, q = idx & 7;
        uint4 v = make_uint4(0u, 0u, 0u, 0u);
        if (base + r < n_nodes) v = *(const uint4*)(xb + (size_t)(base + r) * FDIM + q * 8);
        *(uint4*)(&sH[r * HP + q * 8]) = v;
    }
    __syncthreads();

    int w = tid >> 6;       // wave id 0..3
    int lane = tid & 63;
    int qd = lane >> 4;     // quad 0..3
    int m = lane & 15;
    int arow = (w * 16 + m) * HP;

    f32x4 acc[4];

    // ---- layer 1: G = relu(H @ W1 + b1) ----
    {
        bf16x8 a0 = *(bf16x8*)(&sH[arow + qd * 8]);
        bf16x8 a1 = *(bf16x8*)(&sH[arow + 32 + qd * 8]);
#pragma unroll
        for (int t = 0; t < 4; t++) {
            float bias = sb1[t * 16 + m];
            acc[t] = (f32x4){bias, bias, bias, bias};
            bf16x8 bA = *(bf16x8*)(&sW1t[(t * 16 + m) * HP + qd * 8]);
            bf16x8 bB = *(bf16x8*)(&sW1t[(t * 16 + m) * HP + 32 + qd * 8]);
            acc[t] = __builtin_amdgcn_mfma_f32_16x16x32_bf16(a0, bA, acc[t], 0, 0, 0);
            acc[t] = __builtin_amdgcn_mfma_f32_16x16x32_bf16(a1, bB, acc[t], 0, 0, 0);
        }
#pragma unroll
        for (int t = 0; t < 4; t++)
#pragma unroll
            for (int r = 0; r < 4; r++)
                sH[(w * 16 + qd * 4 + r) * HP + t * 16 + m] = f2bf(fmaxf(acc[t][r], 0.f));
    }

    // ---- layer 2: O = relu(G @ W2 + b2) ----
    {
        bf16x8 a0 = *(bf16x8*)(&sH[arow + qd * 8]);
        bf16x8 a1 = *(bf16x8*)(&sH[arow + 32 + qd * 8]);
#pragma unroll
        for (int t = 0; t < 4; t++) {
            float bias = sb2[t * 16 + m];
            acc[t] = (f32x4){bias, bias, bias, bias};
            bf16x8 bA = *(bf16x8*)(&sW2t[(t * 16 + m) * HP + qd * 8]);
            bf16x8 bB = *(bf16x8*)(&sW2t[(t * 16 + m) * HP + 32 + qd * 8]);
            acc[t] = __builtin_amdgcn_mfma_f32_16x16x32_bf16(a0, bA, acc[t], 0, 0, 0);
            acc[t] = __builtin_amdgcn_mfma_f32_16x16x32_bf16(a1, bB, acc[t], 0, 0, 0);
        }
#pragma unroll
        for (int t = 0; t < 4; t++)
#pragma unroll
            for (int r = 0; r < 4; r++)
                sH[(w * 16 + qd * 4 + r) * HP + t * 16 + m] = f2bf(fmaxf(acc[t][r], 0.f));
    }
    __syncthreads();

    if (!do_final) {
#pragma unroll
        for (int p = 0; p < 2; p++) {
            int idx = tid + p * 256;
            int r = idx >> 3, q = idx & 7;
            if (base + r < n_nodes)
                *(uint4*)(y + (size_t)(base + r) * FDIM + q * 8) = *(uint4*)(&sH[r * HP + q * 8]);
        }
    } else {
        for (int i = tid; i < 64 * 10; i += 256) {
            int nl = i / 10, cc = i % 10;
            int node = base + nl;
            if (node < n_nodes) {
                float s = sbl[cc];
#pragma unroll
                for (int k0 = 0; k0 < FDIM; k0 += 4) {
                    uint2 hp = *(uint2*)(&sH[nl * HP + k0]);
                    s += bflo(hp.x) * sWl[(k0 + 0) * 10 + cc] + bfhi(hp.x) * sWl[(k0 + 1) * 10 + cc]
                       + bflo(hp.y) * sWl[(k0 + 2) * 10 + cc] + bfhi(hp.y) * sWl[(k0 + 3) * 10 + cc];
                }
                out[(size_t)node * 10 + cc] = s;
            }
        }
    }
}

extern "C" void kernel_launch(void* const* d_in, const int* in_sizes, int n_in,
                              void* d_out, int out_size, void* d_ws, size_t ws_size,
                              hipStream_t stream) {
    const float* features = (const float*)d_in[0];
    const int* edges = (const int*)d_in[1];
    int n_nodes = in_sizes[0] / FDIM;          // 50000
    int n_edges = in_sizes[1] / 2;             // 800000
    const int* src = edges;
    const int* dst = edges + n_edges;

    int nbuck = (n_nodes + BNODES - 1) / BNODES;     // 782
    int nchunks = (n_edges + CHUNK - 1) / CHUNK;     // 391

    // workspace: hist | chunk_off | bucket_total | bucket_start | row_ptr | packed | src_sorted | bf16 bufs | wt
    int* hist = (int*)d_ws;
    int* chunk_off = hist + (size_t)nchunks * nbuck;
    int* bucket_total = chunk_off + (size_t)nchunks * nbuck;
    int* bucket_start = bucket_total + nbuck;
    int* row_ptr = bucket_start + nbuck + 1;
    unsigned int* packed = (unsigned int*)(row_ptr + n_nodes + 1);
    int* src_sorted = (int*)(packed + n_edges);
    size_t int_elems = 2 * (size_t)nchunks * nbuck + 2 * (size_t)nbuck + 2
                       + (size_t)n_nodes + 2 * (size_t)n_edges;
    int_elems = (int_elems + 3) & ~(size_t)3;
    size_t buf_elems = (size_t)n_nodes * FDIM;
    unsigned short* hb  = (unsigned short*)((int*)d_ws + int_elems);
    unsigned short* xb0 = hb + buf_elems;
    unsigned short* yA  = xb0 + buf_elems;
    unsigned short* yB  = yA + buf_elems;
    unsigned short* wt  = yB + buf_elems;     // 6 * 4096 bf16 (48 KB)

    dim3 bs(256);
    int n4 = (int)(buf_elems / 4);
    int ncast = (n4 + 255) / 256;          // 3125
    dim3 gs_cph(ncast + 6 + nchunks);      // cast + weight-prep + histogram, one launch
    dim3 gs_gather((n_nodes + 31) / 32);   // 1563
    dim3 gs_tile((n_nodes + 63) / 64);     // 782

    // --- fused cast + weight prep + histogram ---
    cast_prep_hist<<<gs_cph, bs, 0, stream>>>(features, xb0, n4, ncast,
                                              (const float*)d_in[2], (const float*)d_in[4],
                                              (const float*)d_in[6], (const float*)d_in[8],
                                              (const float*)d_in[10], (const float*)d_in[12], wt,
                                              dst, hist, n_edges, nbuck);

    // --- build node-grouped CSR via 2-pass bucket sort (deterministic fill) ---
    scan_chunks<<<nbuck, 512, 0, stream>>>(hist, chunk_off, bucket_total, nchunks, nbuck);
    scan_buckets<<<1, 1024, 0, stream>>>(bucket_total, bucket_start, row_ptr, nbuck, n_nodes, n_edges);
    bucket_fill<<<nchunks, 256, 0, stream>>>(src, dst, bucket_start, chunk_off, packed, n_edges, nbuck);
    sort_bucket<<<nbuck, 256, 0, stream>>>(packed, bucket_start, src_sorted, row_ptr, n_nodes);

    // --- 3 GIN convs, split gather/MFMA-MLP (last MLP fuses the final linear) ---
    const float* Wl = (const float*)d_in[14];
    const float* bl = (const float*)d_in[15];
    const unsigned short* x_cur = xb0;
    unsigned short* outs[3] = {yA, yB, yA};
    for (int conv = 0; conv < 3; conv++) {
        const float* b1 = (const float*)d_in[3 + 4 * conv];
        const float* b2 = (const float*)d_in[5 + 4 * conv];
        const unsigned short* wt1 = wt + (size_t)(2 * conv) * 4096;
        const unsigned short* wt2 = wt + (size_t)(2 * conv + 1) * 4096;
        int fin = (conv == 2) ? 1 : 0;

        gather_bf16<<<gs_gather, bs, 0, stream>>>(x_cur, row_ptr, src_sorted, hb, n_nodes);
        mlp_mfma<<<gs_tile, bs, 0, stream>>>(hb, wt1, b1, wt2, b2, Wl, bl,
                                             outs[conv], (float*)d_out, n_nodes, fin);
        x_cur = outs[conv];
    }
}

// Round 16
// 195.640 us; speedup vs baseline: 1.0386x; 1.0386x over previous
//
#include <hip/hip_runtime.h>
#include <hip/hip_bf16.h>

#define FDIM 64
#define BNODES 64          // nodes per bucket (dst >> 6)
#define CHUNK 4096         // edges per partition chunk (196 chunks -> measured optimum)
#define HP 72              // padded LDS row stride in shorts
#define GCAP 2048          // staged edge-index capacity per gather block (32 nodes)

typedef short bf16x8 __attribute__((ext_vector_type(8)));
typedef float f32x4 __attribute__((ext_vector_type(4)));

__device__ __forceinline__ unsigned short f2bf(float f) {
    unsigned int u = __float_as_uint(f);
    unsigned int r = (u + 0x7fffu + ((u >> 16) & 1u)) >> 16;   // RNE
    return (unsigned short)r;
}
__device__ __forceinline__ float bflo(unsigned int p) { return __uint_as_float(p << 16); }
__device__ __forceinline__ float bfhi(unsigned int p) { return __uint_as_float(p & 0xffff0000u); }

// ---- fused: cast features (blocks [0,ncast)) + transpose 6 weight matrices
// (blocks [ncast,ncast+6)) + per-chunk bucket histogram (blocks [ncast+6, ...)) ----
__global__ __launch_bounds__(256) void cast_prep_hist(const float* __restrict__ x,
                                                      unsigned short* __restrict__ xb, int n4,
                                                      int ncast,
                                                      const float* __restrict__ W10,
                                                      const float* __restrict__ W20,
                                                      const float* __restrict__ W11,
                                                      const float* __restrict__ W21,
                                                      const float* __restrict__ W12,
                                                      const float* __restrict__ W22,
                                                      unsigned short* __restrict__ wt,
                                                      const int* __restrict__ dst,
                                                      int* __restrict__ hist,
                                                      int n_edges, int nbuck) {
    int tid = threadIdx.x;
    if (blockIdx.x < (unsigned)ncast) {
        int i = blockIdx.x * 256 + tid;
        if (i < n4) {
            float4 v = ((const float4*)x)[i];
            uint2 o;
            o.x = (unsigned int)f2bf(v.x) | ((unsigned int)f2bf(v.y) << 16);
            o.y = (unsigned int)f2bf(v.z) | ((unsigned int)f2bf(v.w) << 16);
            ((uint2*)xb)[i] = o;
        }
        return;
    }
    if (blockIdx.x < (unsigned)(ncast + 6)) {
        __shared__ unsigned short s[64 * 64];
        int wsel = blockIdx.x - ncast;     // 0..5
        const float* W;
        switch (wsel) {
            case 0: W = W10; break;
            case 1: W = W20; break;
            case 2: W = W11; break;
            case 3: W = W21; break;
            case 4: W = W12; break;
            default: W = W22; break;
        }
#pragma unroll
        for (int p = 0; p < 4; p++) {
            int idx = tid + p * 256;          // 0..1023
            int k = idx >> 4;
            int n0 = (idx & 15) * 4;
            float4 v = ((const float4*)W)[idx];
            s[(n0 + 0) * 64 + k] = f2bf(v.x);
            s[(n0 + 1) * 64 + k] = f2bf(v.y);
            s[(n0 + 2) * 64 + k] = f2bf(v.z);
            s[(n0 + 3) * 64 + k] = f2bf(v.w);
        }
        __syncthreads();
        uint4* o = (uint4*)(wt + (size_t)wsel * 4096);
#pragma unroll
        for (int p = 0; p < 2; p++) {
            int idx = tid + p * 256;          // 0..511
            o[idx] = ((uint4*)s)[idx];
        }
        return;
    }
    // histogram branch
    {
        __shared__ int lh[1024];
        int chunk = blockIdx.x - ncast - 6;
        for (int i = tid; i < nbuck; i += 256) lh[i] = 0;
        __syncthreads();
        int beg = chunk * CHUNK;
        int end = min(beg + CHUNK, n_edges);
        for (int e = beg + tid; e < end; e += 256)
            atomicAdd(&lh[dst[e] >> 6], 1);
        __syncthreads();
        for (int i = tid; i < nbuck; i += 256)
            hist[(size_t)chunk * nbuck + i] = lh[i];
    }
}

// ---- pass 2a: per-bucket exclusive scan over chunks (nchunks <= 256) ----
__global__ __launch_bounds__(256) void scan_chunks(const int* __restrict__ hist,
                                                   int* __restrict__ chunk_off,
                                                   int* __restrict__ bucket_total,
                                                   int nchunks, int nbuck) {
    __shared__ int s[256];
    int b = blockIdx.x;
    int t = threadIdx.x;
    int v = (t < nchunks) ? hist[(size_t)t * nbuck + b] : 0;
    s[t] = v;
    __syncthreads();
    for (int off = 1; off < 256; off <<= 1) {
        int u = (t >= off) ? s[t - off] : 0;
        __syncthreads();
        s[t] += u;
        __syncthreads();
    }
    if (t < nchunks) chunk_off[(size_t)t * nbuck + b] = s[t] - v;  // exclusive
    if (t == 255) bucket_total[b] = s[255];
}

// ---- pass 2b: exclusive scan of bucket totals ----
__global__ __launch_bounds__(1024) void scan_buckets(const int* __restrict__ bucket_total,
                                                     int* __restrict__ bucket_start,
                                                     int* __restrict__ row_ptr,
                                                     int nbuck, int n_nodes, int n_edges) {
    __shared__ int s[1024];
    int t = threadIdx.x;
    int v = (t < nbuck) ? bucket_total[t] : 0;
    s[t] = v;
    __syncthreads();
    for (int off = 1; off < 1024; off <<= 1) {
        int u = (t >= off) ? s[t - off] : 0;
        __syncthreads();
        s[t] += u;
        __syncthreads();
    }
    if (t < nbuck) bucket_start[t] = s[t] - v;
    if (t == 0) { bucket_start[nbuck] = n_edges; row_ptr[n_nodes] = n_edges; }
}

// ---- pass 3: fill packed edges, (chunk,bucket)-contiguous runs ----
__global__ __launch_bounds__(256) void bucket_fill(const int* __restrict__ src,
                                                   const int* __restrict__ dst,
                                                   const int* __restrict__ bucket_start,
                                                   const int* __restrict__ chunk_off,
                                                   unsigned int* __restrict__ packed,
                                                   int n_edges, int nbuck) {
    __shared__ int cur[1024];
    int chunk = blockIdx.x;
    for (int i = threadIdx.x; i < nbuck; i += 256)
        cur[i] = bucket_start[i] + chunk_off[(size_t)chunk * nbuck + i];
    __syncthreads();
    int beg = chunk * CHUNK;
    int end = min(beg + CHUNK, n_edges);
    for (int e = beg + threadIdx.x; e < end; e += 256) {
        int d = dst[e];
        int b = d >> 6;
        int pos = atomicAdd(&cur[b], 1);
        packed[pos] = (unsigned int)src[e] | ((unsigned int)(d & 63) << 16);
    }
}

// ---- pass 4: within-bucket sort to node granularity + row_ptr emit ----
__global__ __launch_bounds__(256) void sort_bucket(const unsigned int* __restrict__ packed,
                                                   const int* __restrict__ bucket_start,
                                                   int* __restrict__ src_sorted,
                                                   int* __restrict__ row_ptr, int n_nodes) {
    __shared__ int cnt[BNODES];
    __shared__ int cur[BNODES];
    int b = blockIdx.x;
    int beg = bucket_start[b], end = bucket_start[b + 1];
    if (threadIdx.x < BNODES) cnt[threadIdx.x] = 0;
    __syncthreads();
    for (int e = beg + threadIdx.x; e < end; e += 256)
        atomicAdd(&cnt[packed[e] >> 16], 1);
    __syncthreads();
    if (threadIdx.x < 64) {
        int v = cnt[threadIdx.x];
        int inc = v;
#pragma unroll
        for (int off = 1; off < 64; off <<= 1) {
            int u = __shfl_up(inc, off, 64);
            if (threadIdx.x >= off) inc += u;
        }
        cur[threadIdx.x] = beg + inc - v;     // exclusive
        int node = b * BNODES + threadIdx.x;
        if (node < n_nodes) row_ptr[node] = beg + inc - v;
    }
    __syncthreads();
    for (int e = beg + threadIdx.x; e < end; e += 256) {
        unsigned int p = packed[e];
        int pos = atomicAdd(&cur[p >> 16], 1);
        src_sorted[pos] = (int)(p & 0xFFFFu);
    }
}

// gather (bf16 in/out, fp32 accum): 32 nodes/block, 8 threads/node, 16B/lane loads.
__global__ __launch_bounds__(256) void gather_bf16(const unsigned short* __restrict__ xb,
                                                   const int* __restrict__ row_ptr,
                                                   const int* __restrict__ src_sorted,
                                                   unsigned short* __restrict__ hb,
                                                   int n_nodes) {
    __shared__ int sidx[GCAP];
    int base = blockIdx.x * 32;
    int ebeg = row_ptr[base];
    int eend = row_ptr[min(base + 32, n_nodes)];
    int total = eend - ebeg;
    int cnt = min(total, GCAP);
    for (int i = threadIdx.x; i < cnt; i += 256) sidx[i] = src_sorted[ebeg + i];
    __syncthreads();

    int t = threadIdx.x;
    int node = base + (t >> 3);
    if (node >= n_nodes) return;
    int c = (t & 7) * 8;                  // 8 bf16 = 16B per lane
    int dbeg = row_ptr[node] - ebeg;
    int dend = row_ptr[node + 1] - ebeg;
    int dmid = (total <= GCAP) ? dend : min(dend, cnt);

    float acc[8];
    {
        uint4 v = *(const uint4*)(xb + (size_t)node * FDIM + c);
        acc[0] = bflo(v.x); acc[1] = bfhi(v.x);
        acc[2] = bflo(v.y); acc[3] = bfhi(v.y);
        acc[4] = bflo(v.z); acc[5] = bfhi(v.z);
        acc[6] = bflo(v.w); acc[7] = bfhi(v.w);
    }

    int e = dbeg;
    for (; e + 7 < dmid; e += 8) {
        int s[8];
#pragma unroll
        for (int j = 0; j < 8; j++) s[j] = sidx[e + j];
        uint4 v[8];
#pragma unroll
        for (int j = 0; j < 8; j++) v[j] = *(const uint4*)(xb + (size_t)s[j] * FDIM + c);
#pragma unroll
        for (int j = 0; j < 8; j++) {
            acc[0] += bflo(v[j].x); acc[1] += bfhi(v[j].x);
            acc[2] += bflo(v[j].y); acc[3] += bfhi(v[j].y);
            acc[4] += bflo(v[j].z); acc[5] += bfhi(v[j].z);
            acc[6] += bflo(v[j].w); acc[7] += bfhi(v[j].w);
        }
    }
    if (e + 3 < dmid) {
        int s[4];
#pragma unroll
        for (int j = 0; j < 4; j++) s[j] = sidx[e + j];
        uint4 v[4];
#pragma unroll
        for (int j = 0; j < 4; j++) v[j] = *(const uint4*)(xb + (size_t)s[j] * FDIM + c);
#pragma unroll
        for (int j = 0; j < 4; j++) {
            acc[0] += bflo(v[j].x); acc[1] += bfhi(v[j].x);
            acc[2] += bflo(v[j].y); acc[3] += bfhi(v[j].y);
            acc[4] += bflo(v[j].z); acc[5] += bfhi(v[j].z);
            acc[6] += bflo(v[j].w); acc[7] += bfhi(v[j].w);
        }
        e += 4;
    }
    for (; e < dmid; e++) {
        uint4 v = *(const uint4*)(xb + (size_t)sidx[e] * FDIM + c);
        acc[0] += bflo(v.x); acc[1] += bfhi(v.x);
        acc[2] += bflo(v.y); acc[3] += bfhi(v.y);
        acc[4] += bflo(v.z); acc[5] += bfhi(v.z);
        acc[6] += bflo(v.w); acc[7] += bfhi(v.w);
    }
    for (; e < dend; e++) {               // overflow tail (virtually never)
        uint4 v = *(const uint4*)(xb + (size_t)src_sorted[ebeg + e] * FDIM + c);
        acc[0] += bflo(v.x); acc[1] += bfhi(v.x);
        acc[2] += bflo(v.y); acc[3] += bfhi(v.y);
        acc[4] += bflo(v.z); acc[5] += bfhi(v.z);
        acc[6] += bflo(v.w); acc[7] += bfhi(v.w);
    }

    uint4 p;
    p.x = (unsigned int)f2bf(acc[0]) | ((unsigned int)f2bf(acc[1]) << 16);
    p.y = (unsigned int)f2bf(acc[2]) | ((unsigned int)f2bf(acc[3]) << 16);
    p.z = (unsigned int)f2bf(acc[4]) | ((unsigned int)f2bf(acc[5]) << 16);
    p.w = (unsigned int)f2bf(acc[6]) | ((unsigned int)f2bf(acc[7]) << 16);
    *(uint4*)(hb + (size_t)node * FDIM + c) = p;
}

// ---- MFMA MLP over a 64-node tile; weights pre-transposed bf16 [n][k] in global ----
__global__ __launch_bounds__(256) void mlp_mfma(const unsigned short* __restrict__ xb,
        const unsigned short* __restrict__ wt1, const float* __restrict__ b1,
        const unsigned short* __restrict__ wt2, const float* __restrict__ b2,
        const float* __restrict__ Wl, const float* __restrict__ bl,
        unsigned short* __restrict__ y, float* __restrict__ out,
        int n_nodes, int do_final) {
    __shared__ unsigned short sH[64 * HP];      // H -> G -> O (bf16)
    __shared__ unsigned short sW1t[64 * HP];    // W1^T [n][k] bf16
    __shared__ unsigned short sW2t[64 * HP];    // W2^T [n][k] bf16
    __shared__ float sb1[FDIM], sb2[FDIM];
    __shared__ float sWl[FDIM * 10];
    __shared__ float sbl[16];

    int tid = threadIdx.x;
    int base = blockIdx.x * 64;

    {
        const uint4* w1g = (const uint4*)wt1;
        const uint4* w2g = (const uint4*)wt2;
#pragma unroll
        for (int p = 0; p < 2; p++) {
            int idx = tid + p * 256;       // 0..511
            int r = idx >> 3, q = idx & 7;
            *(uint4*)(&sW1t[r * HP + q * 8]) = w1g[idx];
            *(uint4*)(&sW2t[r * HP + q * 8]) = w2g[idx];
        }
    }
    if (tid < FDIM) { sb1[tid] = b1[tid]; sb2[tid] = b2[tid]; }
    if (do_final) {
        for (int i = tid; i < FDIM * 10; i += 256) sWl[i] = Wl[i];
        if (tid < 10) sbl[tid] = bl[tid];
    }
#pragma unroll
    for (int p = 0; p < 2; p++) {
        int idx = tid + p * 256;
        int r = idx >> 3, q = idx & 7;
        uint4 v = make_uint4(0u, 0u, 0u, 0u);
        if (base + r < n_nodes) v = *(const uint4*)(xb + (size_t)(base + r) * FDIM + q * 8);
        *(uint4*)(&sH[r * HP + q * 8]) = v;
    }
    __syncthreads();

    int w = tid >> 6;       // wave id 0..3
    int lane = tid & 63;
    int qd = lane >> 4;     // quad 0..3
    int m = lane & 15;
    int arow = (w * 16 + m) * HP;

    f32x4 acc[4];

    // ---- layer 1: G = relu(H @ W1 + b1) ----
    {
        bf16x8 a0 = *(bf16x8*)(&sH[arow + qd * 8]);
        bf16x8 a1 = *(bf16x8*)(&sH[arow + 32 + qd * 8]);
#pragma unroll
        for (int t = 0; t < 4; t++) {
            float bias = sb1[t * 16 + m];
            acc[t] = (f32x4){bias, bias, bias, bias};
            bf16x8 bA = *(bf16x8*)(&sW1t[(t * 16 + m) * HP + qd * 8]);
            bf16x8 bB = *(bf16x8*)(&sW1t[(t * 16 + m) * HP + 32 + qd * 8]);
            acc[t] = __builtin_amdgcn_mfma_f32_16x16x32_bf16(a0, bA, acc[t], 0, 0, 0);
            acc[t] = __builtin_amdgcn_mfma_f32_16x16x32_bf16(a1, bB, acc[t], 0, 0, 0);
        }
#pragma unroll
        for (int t = 0; t < 4; t++)
#pragma unroll
            for (int r = 0; r < 4; r++)
                sH[(w * 16 + qd * 4 + r) * HP + t * 16 + m] = f2bf(fmaxf(acc[t][r], 0.f));
    }

    // ---- layer 2: O = relu(G @ W2 + b2) ----
    {
        bf16x8 a0 = *(bf16x8*)(&sH[arow + qd * 8]);
        bf16x8 a1 = *(bf16x8*)(&sH[arow + 32 + qd * 8]);
#pragma unroll
        for (int t = 0; t < 4; t++) {
            float bias = sb2[t * 16 + m];
            acc[t] = (f32x4){bias, bias, bias, bias};
            bf16x8 bA = *(bf16x8*)(&sW2t[(t * 16 + m) * HP + qd * 8]);
            bf16x8 bB = *(bf16x8*)(&sW2t[(t * 16 + m) * HP + 32 + qd * 8]);
            acc[t] = __builtin_amdgcn_mfma_f32_16x16x32_bf16(a0, bA, acc[t], 0, 0, 0);
            acc[t] = __builtin_amdgcn_mfma_f32_16x16x32_bf16(a1, bB, acc[t], 0, 0, 0);
        }
#pragma unroll
        for (int t = 0; t < 4; t++)
#pragma unroll
            for (int r = 0; r < 4; r++)
                sH[(w * 16 + qd * 4 + r) * HP + t * 16 + m] = f2bf(fmaxf(acc[t][r], 0.f));
    }
    __syncthreads();

    if (!do_final) {
#pragma unroll
        for (int p = 0; p < 2; p++) {
            int idx = tid + p * 256;
            int r = idx >> 3, q = idx & 7;
            if (base + r < n_nodes)
                *(uint4*)(y + (size_t)(base + r) * FDIM + q * 8) = *(uint4*)(&sH[r * HP + q * 8]);
        }
    } else {
        for (int i = tid; i < 64 * 10; i += 256) {
            int nl = i / 10, cc = i % 10;
            int node = base + nl;
            if (node < n_nodes) {
                float s = sbl[cc];
#pragma unroll
                for (int k0 = 0; k0 < FDIM; k0 += 4) {
                    uint2 hp = *(uint2*)(&sH[nl * HP + k0]);
                    s += bflo(hp.x) * sWl[(k0 + 0) * 10 + cc] + bfhi(hp.x) * sWl[(k0 + 1) * 10 + cc]
                       + bflo(hp.y) * sWl[(k0 + 2) * 10 + cc] + bfhi(hp.y) * sWl[(k0 + 3) * 10 + cc];
                }
                out[(size_t)node * 10 + cc] = s;
            }
        }
    }
}

extern "C" void kernel_launch(void* const* d_in, const int* in_sizes, int n_in,
                              void* d_out, int out_size, void* d_ws, size_t ws_size,
                              hipStream_t stream) {
    const float* features = (const float*)d_in[0];
    const int* edges = (const int*)d_in[1];
    int n_nodes = in_sizes[0] / FDIM;          // 50000
    int n_edges = in_sizes[1] / 2;             // 800000
    const int* src = edges;
    const int* dst = edges + n_edges;

    int nbuck = (n_nodes + BNODES - 1) / BNODES;     // 782
    int nchunks = (n_edges + CHUNK - 1) / CHUNK;     // 196

    // workspace: hist | chunk_off | bucket_total | bucket_start | row_ptr | packed | src_sorted | bf16 bufs | wt
    int* hist = (int*)d_ws;
    int* chunk_off = hist + (size_t)nchunks * nbuck;
    int* bucket_total = chunk_off + (size_t)nchunks * nbuck;
    int* bucket_start = bucket_total + nbuck;
    int* row_ptr = bucket_start + nbuck + 1;
    unsigned int* packed = (unsigned int*)(row_ptr + n_nodes + 1);
    int* src_sorted = (int*)(packed + n_edges);
    size_t int_elems = 2 * (size_t)nchunks * nbuck + 2 * (size_t)nbuck + 2
                       + (size_t)n_nodes + 2 * (size_t)n_edges;
    int_elems = (int_elems + 3) & ~(size_t)3;
    size_t buf_elems = (size_t)n_nodes * FDIM;
    unsigned short* hb  = (unsigned short*)((int*)d_ws + int_elems);
    unsigned short* xb0 = hb + buf_elems;
    unsigned short* yA  = xb0 + buf_elems;
    unsigned short* yB  = yA + buf_elems;
    unsigned short* wt  = yB + buf_elems;     // 6 * 4096 bf16 (48 KB)

    dim3 bs(256);
    int n4 = (int)(buf_elems / 4);
    int ncast = (n4 + 255) / 256;          // 3125
    dim3 gs_cph(ncast + 6 + nchunks);      // cast + weight-prep + histogram, one launch
    dim3 gs_gather((n_nodes + 31) / 32);   // 1563
    dim3 gs_tile((n_nodes + 63) / 64);     // 782

    // --- fused cast + weight prep + histogram ---
    cast_prep_hist<<<gs_cph, bs, 0, stream>>>(features, xb0, n4, ncast,
                                              (const float*)d_in[2], (const float*)d_in[4],
                                              (const float*)d_in[6], (const float*)d_in[8],
                                              (const float*)d_in[10], (const float*)d_in[12], wt,
                                              dst, hist, n_edges, nbuck);

    // --- build node-grouped CSR via 2-pass bucket sort (deterministic fill) ---
    scan_chunks<<<nbuck, 256, 0, stream>>>(hist, chunk_off, bucket_total, nchunks, nbuck);
    scan_buckets<<<1, 1024, 0, stream>>>(bucket_total, bucket_start, row_ptr, nbuck, n_nodes, n_edges);
    bucket_fill<<<nchunks, 256, 0, stream>>>(src, dst, bucket_start, chunk_off, packed, n_edges, nbuck);
    sort_bucket<<<nbuck, 256, 0, stream>>>(packed, bucket_start, src_sorted, row_ptr, n_nodes);

    // --- 3 GIN convs, split gather/MFMA-MLP (last MLP fuses the final linear) ---
    const float* Wl = (const float*)d_in[14];
    const float* bl = (const float*)d_in[15];
    const unsigned short* x_cur = xb0;
    unsigned short* outs[3] = {yA, yB, yA};
    for (int conv = 0; conv < 3; conv++) {
        const float* b1 = (const float*)d_in[3 + 4 * conv];
        const float* b2 = (const float*)d_in[5 + 4 * conv];
        const unsigned short* wt1 = wt + (size_t)(2 * conv) * 4096;
        const unsigned short* wt2 = wt + (size_t)(2 * conv + 1) * 4096;
        int fin = (conv == 2) ? 1 : 0;

        gather_bf16<<<gs_gather, bs, 0, stream>>>(x_cur, row_ptr, src_sorted, hb, n_nodes);
        mlp_mfma<<<gs_tile, bs, 0, stream>>>(hb, wt1, b1, wt2, b2, Wl, bl,
                                             outs[conv], (float*)d_out, n_nodes, fin);
        x_cur = outs[conv];
    }
}

// Round 17
// 192.958 us; speedup vs baseline: 1.0530x; 1.0139x over previous
//
#include <hip/hip_runtime.h>
#include <hip/hip_bf16.h>

#define FDIM 64
#define BNODES 64          // nodes per bucket (dst >> 6)
#define CHUNK 4096         // edges per partition chunk (196 chunks -> measured optimum)
#define HP 72              // padded LDS row stride in shorts
#define GCAP 2048          // staged capacity (bucket mean 1023, sigma 32 -> huge margin)
#define SGT 512            // sort_gather block size (8 waves)

typedef short bf16x8 __attribute__((ext_vector_type(8)));
typedef float f32x4 __attribute__((ext_vector_type(4)));

__device__ __forceinline__ unsigned short f2bf(float f) {
    unsigned int u = __float_as_uint(f);
    unsigned int r = (u + 0x7fffu + ((u >> 16) & 1u)) >> 16;   // RNE
    return (unsigned short)r;
}
__device__ __forceinline__ float bflo(unsigned int p) { return __uint_as_float(p << 16); }
__device__ __forceinline__ float bfhi(unsigned int p) { return __uint_as_float(p & 0xffff0000u); }

// ---- fused: cast features (blocks [0,ncast)) + transpose 6 weight matrices
// (blocks [ncast,ncast+6)) + per-chunk bucket histogram (blocks [ncast+6, ...)) ----
__global__ __launch_bounds__(256) void cast_prep_hist(const float* __restrict__ x,
                                                      unsigned short* __restrict__ xb, int n4,
                                                      int ncast,
                                                      const float* __restrict__ W10,
                                                      const float* __restrict__ W20,
                                                      const float* __restrict__ W11,
                                                      const float* __restrict__ W21,
                                                      const float* __restrict__ W12,
                                                      const float* __restrict__ W22,
                                                      unsigned short* __restrict__ wt,
                                                      const int* __restrict__ dst,
                                                      int* __restrict__ hist,
                                                      int n_edges, int nbuck) {
    int tid = threadIdx.x;
    if (blockIdx.x < (unsigned)ncast) {
        int i = blockIdx.x * 256 + tid;
        if (i < n4) {
            float4 v = ((const float4*)x)[i];
            uint2 o;
            o.x = (unsigned int)f2bf(v.x) | ((unsigned int)f2bf(v.y) << 16);
            o.y = (unsigned int)f2bf(v.z) | ((unsigned int)f2bf(v.w) << 16);
            ((uint2*)xb)[i] = o;
        }
        return;
    }
    if (blockIdx.x < (unsigned)(ncast + 6)) {
        __shared__ unsigned short s[64 * 64];
        int wsel = blockIdx.x - ncast;     // 0..5
        const float* W;
        switch (wsel) {
            case 0: W = W10; break;
            case 1: W = W20; break;
            case 2: W = W11; break;
            case 3: W = W21; break;
            case 4: W = W12; break;
            default: W = W22; break;
        }
#pragma unroll
        for (int p = 0; p < 4; p++) {
            int idx = tid + p * 256;          // 0..1023
            int k = idx >> 4;
            int n0 = (idx & 15) * 4;
            float4 v = ((const float4*)W)[idx];
            s[(n0 + 0) * 64 + k] = f2bf(v.x);
            s[(n0 + 1) * 64 + k] = f2bf(v.y);
            s[(n0 + 2) * 64 + k] = f2bf(v.z);
            s[(n0 + 3) * 64 + k] = f2bf(v.w);
        }
        __syncthreads();
        uint4* o = (uint4*)(wt + (size_t)wsel * 4096);
#pragma unroll
        for (int p = 0; p < 2; p++) {
            int idx = tid + p * 256;          // 0..511
            o[idx] = ((uint4*)s)[idx];
        }
        return;
    }
    // histogram branch
    {
        __shared__ int lh[1024];
        int chunk = blockIdx.x - ncast - 6;
        for (int i = tid; i < nbuck; i += 256) lh[i] = 0;
        __syncthreads();
        int beg = chunk * CHUNK;
        int end = min(beg + CHUNK, n_edges);
        for (int e = beg + tid; e < end; e += 256)
            atomicAdd(&lh[dst[e] >> 6], 1);
        __syncthreads();
        for (int i = tid; i < nbuck; i += 256)
            hist[(size_t)chunk * nbuck + i] = lh[i];
    }
}

// ---- pass 2a: per-bucket exclusive scan over chunks (nchunks <= 256) ----
__global__ __launch_bounds__(256) void scan_chunks(const int* __restrict__ hist,
                                                   int* __restrict__ chunk_off,
                                                   int* __restrict__ bucket_total,
                                                   int nchunks, int nbuck) {
    __shared__ int s[256];
    int b = blockIdx.x;
    int t = threadIdx.x;
    int v = (t < nchunks) ? hist[(size_t)t * nbuck + b] : 0;
    s[t] = v;
    __syncthreads();
    for (int off = 1; off < 256; off <<= 1) {
        int u = (t >= off) ? s[t - off] : 0;
        __syncthreads();
        s[t] += u;
        __syncthreads();
    }
    if (t < nchunks) chunk_off[(size_t)t * nbuck + b] = s[t] - v;  // exclusive
    if (t == 255) bucket_total[b] = s[255];
}

// ---- pass 2b: exclusive scan of bucket totals ----
__global__ __launch_bounds__(1024) void scan_buckets(const int* __restrict__ bucket_total,
                                                     int* __restrict__ bucket_start,
                                                     int* __restrict__ row_ptr,
                                                     int nbuck, int n_nodes, int n_edges) {
    __shared__ int s[1024];
    int t = threadIdx.x;
    int v = (t < nbuck) ? bucket_total[t] : 0;
    s[t] = v;
    __syncthreads();
    for (int off = 1; off < 1024; off <<= 1) {
        int u = (t >= off) ? s[t - off] : 0;
        __syncthreads();
        s[t] += u;
        __syncthreads();
    }
    if (t < nbuck) bucket_start[t] = s[t] - v;
    if (t == 0) { bucket_start[nbuck] = n_edges; row_ptr[n_nodes] = n_edges; }
}

// ---- pass 3: fill packed edges, (chunk,bucket)-contiguous runs ----
__global__ __launch_bounds__(256) void bucket_fill(const int* __restrict__ src,
                                                   const int* __restrict__ dst,
                                                   const int* __restrict__ bucket_start,
                                                   const int* __restrict__ chunk_off,
                                                   unsigned int* __restrict__ packed,
                                                   int n_edges, int nbuck) {
    __shared__ int cur[1024];
    int chunk = blockIdx.x;
    for (int i = threadIdx.x; i < nbuck; i += 256)
        cur[i] = bucket_start[i] + chunk_off[(size_t)chunk * nbuck + i];
    __syncthreads();
    int beg = chunk * CHUNK;
    int end = min(beg + CHUNK, n_edges);
    for (int e = beg + threadIdx.x; e < end; e += 256) {
        int d = dst[e];
        int b = d >> 6;
        int pos = atomicAdd(&cur[b], 1);
        packed[pos] = (unsigned int)src[e] | ((unsigned int)(d & 63) << 16);
    }
}

// ---- fused pass 4 + conv-1 gather: one block per bucket ----
// Sort the bucket's edges to node granularity in LDS (emitting row_ptr +
// src_sorted for convs 2/3), then gather all 64 nodes directly from LDS.
__global__ __launch_bounds__(SGT) void sort_gather(const unsigned int* __restrict__ packed,
                                                   const int* __restrict__ bucket_start,
                                                   const unsigned short* __restrict__ xb,
                                                   int* __restrict__ src_sorted,
                                                   int* __restrict__ row_ptr,
                                                   unsigned short* __restrict__ hb,
                                                   int n_nodes) {
    __shared__ unsigned int spk[GCAP];
    __shared__ int sidx[GCAP];
    __shared__ int cnt[BNODES];
    __shared__ int nbeg[BNODES];
    __shared__ int cur[BNODES];
    int b = blockIdx.x;
    int tid = threadIdx.x;
    int ebeg = bucket_start[b], eend = bucket_start[b + 1];
    int total = eend - ebeg;
    bool fits = (total <= GCAP);
    if (tid < BNODES) cnt[tid] = 0;
    if (fits)
        for (int i = tid; i < total; i += SGT) spk[i] = packed[ebeg + i];
    __syncthreads();
    if (fits) {
        for (int i = tid; i < total; i += SGT) atomicAdd(&cnt[spk[i] >> 16], 1);
    } else {
        for (int e = ebeg + tid; e < eend; e += SGT) atomicAdd(&cnt[packed[e] >> 16], 1);
    }
    __syncthreads();
    if (tid < 64) {      // first wave: shfl inclusive scan over 64 degrees
        int v = cnt[tid];
        int inc = v;
#pragma unroll
        for (int off = 1; off < 64; off <<= 1) {
            int u = __shfl_up(inc, off, 64);
            if (tid >= off) inc += u;
        }
        int ex = inc - v;
        nbeg[tid] = ex;
        cur[tid] = ex;
        int node = b * BNODES + tid;
        if (node < n_nodes) row_ptr[node] = ebeg + ex;
    }
    __syncthreads();
    if (fits) {
        for (int i = tid; i < total; i += SGT) {
            unsigned int p = spk[i];
            int pos = atomicAdd(&cur[p >> 16], 1);
            int s = (int)(p & 0xFFFFu);
            sidx[pos] = s;
            src_sorted[ebeg + pos] = s;      // for convs 2/3
        }
    } else {
        for (int e = ebeg + tid; e < eend; e += SGT) {
            unsigned int p = packed[e];
            int pos = atomicAdd(&cur[p >> 16], 1);
            src_sorted[ebeg + pos] = (int)(p & 0xFFFFu);
        }
    }
    __syncthreads();   // sorted indices visible (LDS or global) to whole block

    // gather: 64 nodes, 8 threads/node, 16B/lane, 8-deep in flight
    int nl = tid >> 3;
    int node = b * BNODES + nl;
    if (node >= n_nodes) return;
    int c = (tid & 7) * 8;
    int dbeg = nbeg[nl];
    int dend = dbeg + cnt[nl];

    float acc[8];
    {
        uint4 v = *(const uint4*)(xb + (size_t)node * FDIM + c);
        acc[0] = bflo(v.x); acc[1] = bfhi(v.x);
        acc[2] = bflo(v.y); acc[3] = bfhi(v.y);
        acc[4] = bflo(v.z); acc[5] = bfhi(v.z);
        acc[6] = bflo(v.w); acc[7] = bfhi(v.w);
    }

    if (fits) {
        int e = dbeg;
        for (; e + 7 < dend; e += 8) {
            int s[8];
#pragma unroll
            for (int j = 0; j < 8; j++) s[j] = sidx[e + j];
            uint4 v[8];
#pragma unroll
            for (int j = 0; j < 8; j++) v[j] = *(const uint4*)(xb + (size_t)s[j] * FDIM + c);
#pragma unroll
            for (int j = 0; j < 8; j++) {
                acc[0] += bflo(v[j].x); acc[1] += bfhi(v[j].x);
                acc[2] += bflo(v[j].y); acc[3] += bfhi(v[j].y);
                acc[4] += bflo(v[j].z); acc[5] += bfhi(v[j].z);
                acc[6] += bflo(v[j].w); acc[7] += bfhi(v[j].w);
            }
        }
        if (e + 3 < dend) {
            int s[4];
#pragma unroll
            for (int j = 0; j < 4; j++) s[j] = sidx[e + j];
            uint4 v[4];
#pragma unroll
            for (int j = 0; j < 4; j++) v[j] = *(const uint4*)(xb + (size_t)s[j] * FDIM + c);
#pragma unroll
            for (int j = 0; j < 4; j++) {
                acc[0] += bflo(v[j].x); acc[1] += bfhi(v[j].x);
                acc[2] += bflo(v[j].y); acc[3] += bfhi(v[j].y);
                acc[4] += bflo(v[j].z); acc[5] += bfhi(v[j].z);
                acc[6] += bflo(v[j].w); acc[7] += bfhi(v[j].w);
            }
            e += 4;
        }
        for (; e < dend; e++) {
            uint4 v = *(const uint4*)(xb + (size_t)sidx[e] * FDIM + c);
            acc[0] += bflo(v.x); acc[1] += bfhi(v.x);
            acc[2] += bflo(v.y); acc[3] += bfhi(v.y);
            acc[4] += bflo(v.z); acc[5] += bfhi(v.z);
            acc[6] += bflo(v.w); acc[7] += bfhi(v.w);
        }
    } else {
        for (int e = dbeg; e < dend; e++) {
            uint4 v = *(const uint4*)(xb + (size_t)src_sorted[ebeg + e] * FDIM + c);
            acc[0] += bflo(v.x); acc[1] += bfhi(v.x);
            acc[2] += bflo(v.y); acc[3] += bfhi(v.y);
            acc[4] += bflo(v.z); acc[5] += bfhi(v.z);
            acc[6] += bflo(v.w); acc[7] += bfhi(v.w);
        }
    }

    uint4 p;
    p.x = (unsigned int)f2bf(acc[0]) | ((unsigned int)f2bf(acc[1]) << 16);
    p.y = (unsigned int)f2bf(acc[2]) | ((unsigned int)f2bf(acc[3]) << 16);
    p.z = (unsigned int)f2bf(acc[4]) | ((unsigned int)f2bf(acc[5]) << 16);
    p.w = (unsigned int)f2bf(acc[6]) | ((unsigned int)f2bf(acc[7]) << 16);
    *(uint4*)(hb + (size_t)node * FDIM + c) = p;
}

// gather (bf16 in/out, fp32 accum): 32 nodes/block, 8 threads/node, 16B/lane loads.
__global__ __launch_bounds__(256) void gather_bf16(const unsigned short* __restrict__ xb,
                                                   const int* __restrict__ row_ptr,
                                                   const int* __restrict__ src_sorted,
                                                   unsigned short* __restrict__ hb,
                                                   int n_nodes) {
    __shared__ int sidx[GCAP];
    int base = blockIdx.x * 32;
    int ebeg = row_ptr[base];
    int eend = row_ptr[min(base + 32, n_nodes)];
    int total = eend - ebeg;
    int cnt = min(total, GCAP);
    for (int i = threadIdx.x; i < cnt; i += 256) sidx[i] = src_sorted[ebeg + i];
    __syncthreads();

    int t = threadIdx.x;
    int node = base + (t >> 3);
    if (node >= n_nodes) return;
    int c = (t & 7) * 8;                  // 8 bf16 = 16B per lane
    int dbeg = row_ptr[node] - ebeg;
    int dend = row_ptr[node + 1] - ebeg;
    int dmid = (total <= GCAP) ? dend : min(dend, cnt);

    float acc[8];
    {
        uint4 v = *(const uint4*)(xb + (size_t)node * FDIM + c);
        acc[0] = bflo(v.x); acc[1] = bfhi(v.x);
        acc[2] = bflo(v.y); acc[3] = bfhi(v.y);
        acc[4] = bflo(v.z); acc[5] = bfhi(v.z);
        acc[6] = bflo(v.w); acc[7] = bfhi(v.w);
    }

    int e = dbeg;
    for (; e + 7 < dmid; e += 8) {
        int s[8];
#pragma unroll
        for (int j = 0; j < 8; j++) s[j] = sidx[e + j];
        uint4 v[8];
#pragma unroll
        for (int j = 0; j < 8; j++) v[j] = *(const uint4*)(xb + (size_t)s[j] * FDIM + c);
#pragma unroll
        for (int j = 0; j < 8; j++) {
            acc[0] += bflo(v[j].x); acc[1] += bfhi(v[j].x);
            acc[2] += bflo(v[j].y); acc[3] += bfhi(v[j].y);
            acc[4] += bflo(v[j].z); acc[5] += bfhi(v[j].z);
            acc[6] += bflo(v[j].w); acc[7] += bfhi(v[j].w);
        }
    }
    if (e + 3 < dmid) {
        int s[4];
#pragma unroll
        for (int j = 0; j < 4; j++) s[j] = sidx[e + j];
        uint4 v[4];
#pragma unroll
        for (int j = 0; j < 4; j++) v[j] = *(const uint4*)(xb + (size_t)s[j] * FDIM + c);
#pragma unroll
        for (int j = 0; j < 4; j++) {
            acc[0] += bflo(v[j].x); acc[1] += bfhi(v[j].x);
            acc[2] += bflo(v[j].y); acc[3] += bfhi(v[j].y);
            acc[4] += bflo(v[j].z); acc[5] += bfhi(v[j].z);
            acc[6] += bflo(v[j].w); acc[7] += bfhi(v[j].w);
        }
        e += 4;
    }
    for (; e < dmid; e++) {
        uint4 v = *(const uint4*)(xb + (size_t)sidx[e] * FDIM + c);
        acc[0] += bflo(v.x); acc[1] += bfhi(v.x);
        acc[2] += bflo(v.y); acc[3] += bfhi(v.y);
        acc[4] += bflo(v.z); acc[5] += bfhi(v.z);
        acc[6] += bflo(v.w); acc[7] += bfhi(v.w);
    }
    for (; e < dend; e++) {               // overflow tail (virtually never)
        uint4 v = *(const uint4*)(xb + (size_t)src_sorted[ebeg + e] * FDIM + c);
        acc[0] += bflo(v.x); acc[1] += bfhi(v.x);
        acc[2] += bflo(v.y); acc[3] += bfhi(v.y);
        acc[4] += bflo(v.z); acc[5] += bfhi(v.z);
        acc[6] += bflo(v.w); acc[7] += bfhi(v.w);
    }

    uint4 p;
    p.x = (unsigned int)f2bf(acc[0]) | ((unsigned int)f2bf(acc[1]) << 16);
    p.y = (unsigned int)f2bf(acc[2]) | ((unsigned int)f2bf(acc[3]) << 16);
    p.z = (unsigned int)f2bf(acc[4]) | ((unsigned int)f2bf(acc[5]) << 16);
    p.w = (unsigned int)f2bf(acc[6]) | ((unsigned int)f2bf(acc[7]) << 16);
    *(uint4*)(hb + (size_t)node * FDIM + c) = p;
}

// ---- MFMA MLP over a 64-node tile; weights pre-transposed bf16 [n][k] in global ----
__global__ __launch_bounds__(256) void mlp_mfma(const unsigned short* __restrict__ xb,
        const unsigned short* __restrict__ wt1, const float* __restrict__ b1,
        const unsigned short* __restrict__ wt2, const float* __restrict__ b2,
        const float* __restrict__ Wl, const float* __restrict__ bl,
        unsigned short* __restrict__ y, float* __restrict__ out,
        int n_nodes, int do_final) {
    __shared__ unsigned short sH[64 * HP];      // H -> G -> O (bf16)
    __shared__ unsigned short sW1t[64 * HP];    // W1^T [n][k] bf16
    __shared__ unsigned short sW2t[64 * HP];    // W2^T [n][k] bf16
    __shared__ float sb1[FDIM], sb2[FDIM];
    __shared__ float sWl[FDIM * 10];
    __shared__ float sbl[16];

    int tid = threadIdx.x;
    int base = blockIdx.x * 64;

    {
        const uint4* w1g = (const uint4*)wt1;
        const uint4* w2g = (const uint4*)wt2;
#pragma unroll
        for (int p = 0; p < 2; p++) {
            int idx = tid + p * 256;       // 0..511
            int r = idx >> 3, q = idx & 7;
            *(uint4*)(&sW1t[r * HP + q * 8]) = w1g[idx];
            *(uint4*)(&sW2t[r * HP + q * 8]) = w2g[idx];
        }
    }
    if (tid < FDIM) { sb1[tid] = b1[tid]; sb2[tid] = b2[tid]; }
    if (do_final) {
        for (int i = tid; i < FDIM * 10; i += 256) sWl[i] = Wl[i];
        if (tid < 10) sbl[tid] = bl[tid];
    }
#pragma unroll
    for (int p = 0; p < 2; p++) {
        int idx = tid + p * 256;
        int r = idx >> 3, q = idx & 7;
        uint4 v = make_uint4(0u, 0u, 0u, 0u);
        if (base + r < n_nodes) v = *(const uint4*)(xb + (size_t)(base + r) * FDIM + q * 8);
        *(uint4*)(&sH[r * HP + q * 8]) = v;
    }
    __syncthreads();

    int w = tid >> 6;       // wave id 0..3
    int lane = tid & 63;
    int qd = lane >> 4;     // quad 0..3
    int m = lane & 15;
    int arow = (w * 16 + m) * HP;

    f32x4 acc[4];

    // ---- layer 1: G = relu(H @ W1 + b1) ----
    {
        bf16x8 a0 = *(bf16x8*)(&sH[arow + qd * 8]);
        bf16x8 a1 = *(bf16x8*)(&sH[arow + 32 + qd * 8]);
#pragma unroll
        for (int t = 0; t < 4; t++) {
            float bias = sb1[t * 16 + m];
            acc[t] = (f32x4){bias, bias, bias, bias};
            bf16x8 bA = *(bf16x8*)(&sW1t[(t * 16 + m) * HP + qd * 8]);
            bf16x8 bB = *(bf16x8*)(&sW1t[(t * 16 + m) * HP + 32 + qd * 8]);
            acc[t] = __builtin_amdgcn_mfma_f32_16x16x32_bf16(a0, bA, acc[t], 0, 0, 0);
            acc[t] = __builtin_amdgcn_mfma_f32_16x16x32_bf16(a1, bB, acc[t], 0, 0, 0);
        }
#pragma unroll
        for (int t = 0; t < 4; t++)
#pragma unroll
            for (int r = 0; r < 4; r++)
                sH[(w * 16 + qd * 4 + r) * HP + t * 16 + m] = f2bf(fmaxf(acc[t][r], 0.f));
    }

    // ---- layer 2: O = relu(G @ W2 + b2) ----
    {
        bf16x8 a0 = *(bf16x8*)(&sH[arow + qd * 8]);
        bf16x8 a1 = *(bf16x8*)(&sH[arow + 32 + qd * 8]);
#pragma unroll
        for (int t = 0; t < 4; t++) {
            float bias = sb2[t * 16 + m];
            acc[t] = (f32x4){bias, bias, bias, bias};
            bf16x8 bA = *(bf16x8*)(&sW2t[(t * 16 + m) * HP + qd * 8]);
            bf16x8 bB = *(bf16x8*)(&sW2t[(t * 16 + m) * HP + 32 + qd * 8]);
            acc[t] = __builtin_amdgcn_mfma_f32_16x16x32_bf16(a0, bA, acc[t], 0, 0, 0);
            acc[t] = __builtin_amdgcn_mfma_f32_16x16x32_bf16(a1, bB, acc[t], 0, 0, 0);
        }
#pragma unroll
        for (int t = 0; t < 4; t++)
#pragma unroll
            for (int r = 0; r < 4; r++)
                sH[(w * 16 + qd * 4 + r) * HP + t * 16 + m] = f2bf(fmaxf(acc[t][r], 0.f));
    }
    __syncthreads();

    if (!do_final) {
#pragma unroll
        for (int p = 0; p < 2; p++) {
            int idx = tid + p * 256;
            int r = idx >> 3, q = idx & 7;
            if (base + r < n_nodes)
                *(uint4*)(y + (size_t)(base + r) * FDIM + q * 8) = *(uint4*)(&sH[r * HP + q * 8]);
        }
    } else {
        for (int i = tid; i < 64 * 10; i += 256) {
            int nl = i / 10, cc = i % 10;
            int node = base + nl;
            if (node < n_nodes) {
                float s = sbl[cc];
#pragma unroll
                for (int k0 = 0; k0 < FDIM; k0 += 4) {
                    uint2 hp = *(uint2*)(&sH[nl * HP + k0]);
                    s += bflo(hp.x) * sWl[(k0 + 0) * 10 + cc] + bfhi(hp.x) * sWl[(k0 + 1) * 10 + cc]
                       + bflo(hp.y) * sWl[(k0 + 2) * 10 + cc] + bfhi(hp.y) * sWl[(k0 + 3) * 10 + cc];
                }
                out[(size_t)node * 10 + cc] = s;
            }
        }
    }
}

extern "C" void kernel_launch(void* const* d_in, const int* in_sizes, int n_in,
                              void* d_out, int out_size, void* d_ws, size_t ws_size,
                              hipStream_t stream) {
    const float* features = (const float*)d_in[0];
    const int* edges = (const int*)d_in[1];
    int n_nodes = in_sizes[0] / FDIM;          // 50000
    int n_edges = in_sizes[1] / 2;             // 800000
    const int* src = edges;
    const int* dst = edges + n_edges;

    int nbuck = (n_nodes + BNODES - 1) / BNODES;     // 782
    int nchunks = (n_edges + CHUNK - 1) / CHUNK;     // 196

    // workspace: hist | chunk_off | bucket_total | bucket_start | row_ptr | packed | src_sorted | bf16 bufs | wt
    int* hist = (int*)d_ws;
    int* chunk_off = hist + (size_t)nchunks * nbuck;
    int* bucket_total = chunk_off + (size_t)nchunks * nbuck;
    int* bucket_start = bucket_total + nbuck;
    int* row_ptr = bucket_start + nbuck + 1;
    unsigned int* packed = (unsigned int*)(row_ptr + n_nodes + 1);
    int* src_sorted = (int*)(packed + n_edges);
    size_t int_elems = 2 * (size_t)nchunks * nbuck + 2 * (size_t)nbuck + 2
                       + (size_t)n_nodes + 2 * (size_t)n_edges;
    int_elems = (int_elems + 3) & ~(size_t)3;
    size_t buf_elems = (size_t)n_nodes * FDIM;
    unsigned short* hb  = (unsigned short*)((int*)d_ws + int_elems);
    unsigned short* xb0 = hb + buf_elems;
    unsigned short* yA  = xb0 + buf_elems;
    unsigned short* yB  = yA + buf_elems;
    unsigned short* wt  = yB + buf_elems;     // 6 * 4096 bf16 (48 KB)

    dim3 bs(256);
    int n4 = (int)(buf_elems / 4);
    int ncast = (n4 + 255) / 256;          // 3125
    dim3 gs_cph(ncast + 6 + nchunks);      // cast + weight-prep + histogram, one launch
    dim3 gs_gather((n_nodes + 31) / 32);   // 1563
    dim3 gs_tile((n_nodes + 63) / 64);     // 782

    // --- fused cast + weight prep + histogram ---
    cast_prep_hist<<<gs_cph, bs, 0, stream>>>(features, xb0, n4, ncast,
                                              (const float*)d_in[2], (const float*)d_in[4],
                                              (const float*)d_in[6], (const float*)d_in[8],
                                              (const float*)d_in[10], (const float*)d_in[12], wt,
                                              dst, hist, n_edges, nbuck);

    // --- build node-grouped CSR ---
    scan_chunks<<<nbuck, 256, 0, stream>>>(hist, chunk_off, bucket_total, nchunks, nbuck);
    scan_buckets<<<1, 1024, 0, stream>>>(bucket_total, bucket_start, row_ptr, nbuck, n_nodes, n_edges);
    bucket_fill<<<nchunks, 256, 0, stream>>>(src, dst, bucket_start, chunk_off, packed, n_edges, nbuck);

    const float* Wl = (const float*)d_in[14];
    const float* bl = (const float*)d_in[15];

    // --- conv 1: fused sort + gather, then MFMA MLP ---
    sort_gather<<<nbuck, SGT, 0, stream>>>(packed, bucket_start, xb0,
                                           src_sorted, row_ptr, hb, n_nodes);
    mlp_mfma<<<gs_tile, bs, 0, stream>>>(hb, wt, (const float*)d_in[3],
                                         wt + 4096, (const float*)d_in[5], Wl, bl,
                                         yA, (float*)d_out, n_nodes, 0);

    // --- convs 2,3: split gather / MFMA MLP (last fuses the final linear) ---
    const unsigned short* x_cur = yA;
    unsigned short* outs2[2] = {yB, yA};
    for (int conv = 1; conv < 3; conv++) {
        const float* b1 = (const float*)d_in[3 + 4 * conv];
        const float* b2 = (const float*)d_in[5 + 4 * conv];
        const unsigned short* wt1 = wt + (size_t)(2 * conv) * 4096;
        const unsigned short* wt2 = wt + (size_t)(2 * conv + 1) * 4096;
        int fin = (conv == 2) ? 1 : 0;

        gather_bf16<<<gs_gather, bs, 0, stream>>>(x_cur, row_ptr, src_sorted, hb, n_nodes);
        mlp_mfma<<<gs_tile, bs, 0, stream>>>(hb, wt1, b1, wt2, b2, Wl, bl,
                                             outs2[conv - 1], (float*)d_out, n_nodes, fin);
        x_cur = outs2[conv - 1];
    }
}